// Round 2
// baseline (76.581 us; speedup 1.0000x reference)
//
#include <hip/hip_runtime.h>

#define N_DOCS 500000
#define N_WORDS 100000
#define EMB 128
#define BATCH 16384
#define CTX 8
#define K 6
#define CAP 16
#define OVF_MAX 1024

// ---------------------------------------------------------------------------
// K0: zero the per-word counters + overflow counter.
// ---------------------------------------------------------------------------
__global__ __launch_bounds__(256) void k0_zero(int* __restrict__ cnt, int* __restrict__ ovf_cnt) {
    int i = blockIdx.x * 256 + threadIdx.x;
    if (i < N_WORDS) cnt[i] = 0;
    if (i == 0) *ovf_cnt = 0;
}

// ---------------------------------------------------------------------------
// K1: (a) x[b] = D[doc[b]] + sum_c W[ctx[b,c]]  (one wave per b, float2/lane)
//     (b) inverted-index fill: pos = atomicAdd(cnt[w]); idx[w*CAP+pos] = pair
// Block = 256 = 4 waves = 4 batch rows; threads 0..23 also file the 4*6 pairs.
// ---------------------------------------------------------------------------
__global__ __launch_bounds__(256) void k1_x_and_fill(
    const float* __restrict__ D, const float* __restrict__ W,
    const int* __restrict__ ctx_ids, const int* __restrict__ doc_ids,
    const int* __restrict__ tn_ids, float* __restrict__ x,
    int* __restrict__ cnt, int* __restrict__ idx,
    int* __restrict__ ovf_cnt, int* __restrict__ ovf) {
    const int t = threadIdx.x;
    const int wave = t >> 6, lane = t & 63;
    const int b = blockIdx.x * 4 + wave;

    // ---- inverted index fill (independent of x) ----
    if (t < 4 * K) {
        const int p = blockIdx.x * 4 * K + t;   // pair id = b*K + k
        const int w = tn_ids[p];
        const int pos = atomicAdd(&cnt[w], 1);
        if (pos < CAP) idx[w * CAP + pos] = p;
        else {
            const int o = atomicAdd(ovf_cnt, 1);
            if (o < OVF_MAX) ovf[o] = p;
        }
    }

    // ---- x row ----
    const float2* Drow = (const float2*)(D + (size_t)doc_ids[b] * EMB);
    float2 xx = Drow[lane];
#pragma unroll
    for (int c = 0; c < CTX; ++c) {
        const int id = ctx_ids[b * CTX + c];
        const float2 w2 = ((const float2*)(W + (size_t)id * EMB))[lane];
        xx.x += w2.x;
        xx.y += w2.y;
    }
    ((float2*)(x + (size_t)b * EMB))[lane] = xx;
}

// ---------------------------------------------------------------------------
// K2: stream Wp coalesced once. Each block stages a 64-word x 128-dim column
// tile into LDS (padded rows), then each wave serves 16 words' pairs:
// out[p] = x[b] . col(w), 64-lane shuffle reduce.
// ---------------------------------------------------------------------------
__global__ __launch_bounds__(256) void k2_stream_dot(
    const float* __restrict__ Wp, const float* __restrict__ x,
    const int* __restrict__ cnt, const int* __restrict__ idx,
    const int* __restrict__ ovf_cnt, const int* __restrict__ ovf,
    const int* __restrict__ tn_ids, float* __restrict__ out) {
    __shared__ float tile[64 * 130];  // tile[wl*130 + e], padded to kill bank conflicts
    const int t = threadIdx.x;
    const int w0 = blockIdx.x * 64;

    // load: thread reads float2 across words. wi = word-pair index, e = dim.
    const int wi = t & 31;         // covers 64 words as pairs
    const int e_base = t >> 5;     // 0..7
    if (w0 + 2 * wi + 1 < N_WORDS) {
#pragma unroll
        for (int j = 0; j < 16; ++j) {
            const int e = e_base + 8 * j;
            const float2 v = *(const float2*)(Wp + (size_t)e * N_WORDS + w0 + 2 * wi);
            tile[(2 * wi) * 130 + e] = v.x;
            tile[(2 * wi + 1) * 130 + e] = v.y;
        }
    }
    __syncthreads();

    const int wave = t >> 6, lane = t & 63;
#pragma unroll 1
    for (int i = 0; i < 16; ++i) {
        const int wl = wave * 16 + i;
        const int w = w0 + wl;
        if (w >= N_WORDS) break;
        int c = cnt[w];
        if (c == 0) continue;
        if (c > CAP) c = CAP;
        const float2 cc = ((const float2*)(tile + wl * 130))[lane];
#pragma unroll 1
        for (int q = 0; q < c; ++q) {
            const int p = idx[w * CAP + q];
            const int b = p / K;
            const float2 xv = ((const float2*)(x + (size_t)b * EMB))[lane];
            float s = xv.x * cc.x + xv.y * cc.y;
#pragma unroll
            for (int off = 32; off > 0; off >>= 1) s += __shfl_down(s, off, 64);
            if (lane == 0) out[p] = s;
        }
    }

    // overflow pairs (expected zero): strided column reads, block 0 wave 0
    if (blockIdx.x == 0 && wave == 0) {
        int n = *ovf_cnt;
        if (n > OVF_MAX) n = OVF_MAX;
        for (int i = 0; i < n; ++i) {
            const int p = ovf[i];
            const int w = tn_ids[p];
            const int b = p / K;
            const float a0 = Wp[(size_t)(2 * lane) * N_WORDS + w];
            const float a1 = Wp[(size_t)(2 * lane + 1) * N_WORDS + w];
            const float2 xv = ((const float2*)(x + (size_t)b * EMB))[lane];
            float s = xv.x * a0 + xv.y * a1;
#pragma unroll
            for (int off = 32; off > 0; off >>= 1) s += __shfl_down(s, off, 64);
            if (lane == 0) out[p] = s;
        }
    }
}

// ---------------------------------------------------------------------------
// Fallback (no workspace): direct strided column gather.
// ---------------------------------------------------------------------------
__global__ __launch_bounds__(256) void nce_direct(
    const float* __restrict__ D, const float* __restrict__ W,
    const float* __restrict__ Wp, const int* __restrict__ ctx_ids,
    const int* __restrict__ doc_ids, const int* __restrict__ tn_ids,
    float* __restrict__ out) {
    const int wave = threadIdx.x >> 6, lane = threadIdx.x & 63;
    const int b = blockIdx.x * 4 + wave;
    if (b >= BATCH) return;
    float2 xx = ((const float2*)(D + (size_t)doc_ids[b] * EMB))[lane];
#pragma unroll
    for (int c = 0; c < CTX; ++c) {
        const float2 w2 = ((const float2*)(W + (size_t)ctx_ids[b * CTX + c] * EMB))[lane];
        xx.x += w2.x;
        xx.y += w2.y;
    }
#pragma unroll
    for (int k = 0; k < K; ++k) {
        const int id = tn_ids[b * K + k];
        float s = xx.x * Wp[(size_t)(2 * lane) * N_WORDS + id] +
                  xx.y * Wp[(size_t)(2 * lane + 1) * N_WORDS + id];
#pragma unroll
        for (int off = 32; off > 0; off >>= 1) s += __shfl_down(s, off, 64);
        if (lane == 0) out[b * K + k] = s;
    }
}

extern "C" void kernel_launch(void* const* d_in, const int* in_sizes, int n_in,
                              void* d_out, int out_size, void* d_ws, size_t ws_size,
                              hipStream_t stream) {
    const float* D  = (const float*)d_in[0];
    const float* W  = (const float*)d_in[1];
    const float* Wp = (const float*)d_in[2];
    const int* ctx  = (const int*)d_in[3];
    const int* doc  = (const int*)d_in[4];
    const int* tn   = (const int*)d_in[5];
    float* out = (float*)d_out;

    // ws layout (256B-aligned)
    const size_t x_off   = 0;
    const size_t x_sz    = (size_t)BATCH * EMB * sizeof(float);          // 8 MB
    const size_t cnt_off = (x_off + x_sz + 255) & ~(size_t)255;
    const size_t cnt_sz  = (size_t)N_WORDS * sizeof(int);                // 400 KB
    const size_t idx_off = (cnt_off + cnt_sz + 255) & ~(size_t)255;
    const size_t idx_sz  = (size_t)N_WORDS * CAP * sizeof(int);         // 6.4 MB
    const size_t ovc_off = (idx_off + idx_sz + 255) & ~(size_t)255;
    const size_t ovf_off = (ovc_off + 256 + 255) & ~(size_t)255;
    const size_t need    = ovf_off + OVF_MAX * sizeof(int);

    if (ws_size >= need) {
        char* ws = (char*)d_ws;
        float* x    = (float*)(ws + x_off);
        int* cnt    = (int*)(ws + cnt_off);
        int* idx    = (int*)(ws + idx_off);
        int* ovc    = (int*)(ws + ovc_off);
        int* ovf    = (int*)(ws + ovf_off);

        k0_zero<<<(N_WORDS + 255) / 256, 256, 0, stream>>>(cnt, ovc);
        k1_x_and_fill<<<BATCH / 4, 256, 0, stream>>>(D, W, ctx, doc, tn, x, cnt, idx, ovc, ovf);
        k2_stream_dot<<<(N_WORDS + 63) / 64, 256, 0, stream>>>(Wp, x, cnt, idx, ovc, ovf, tn, out);
    } else {
        nce_direct<<<BATCH / 4, 256, 0, stream>>>(D, W, Wp, ctx, doc, tn, out);
    }
}

// Round 3
// 67.350 us; speedup vs baseline: 1.1371x; 1.1371x over previous
//
#include <hip/hip_runtime.h>

#define N_DOCS 500000
#define N_WORDS 100000
#define EMB 128
#define BATCH 16384
#define CTX 8
#define K 6
#define CAP 16
#define OVF_MAX 1024
#define TILE_W 64
#define TSTRIDE 132  // even (float2-aligned); bank pattern 2-way = free

// ---------------------------------------------------------------------------
// K0: zero per-word counters + overflow counter (ws is poisoned, not zeroed).
// ---------------------------------------------------------------------------
__global__ __launch_bounds__(256) void k0_zero(int* __restrict__ cnt, int* __restrict__ ovc) {
    int i = blockIdx.x * 256 + threadIdx.x;
    if (i < N_WORDS) cnt[i] = 0;
    if (i == 0) *ovc = 0;
}

// ---------------------------------------------------------------------------
// K1: x[b] = D[doc[b]] + sum_c W[ctx[b,c]]  (one wave per b, float2/lane)
//     + inverted-index fill (threads 0..23 file this block's 24 pairs).
// ---------------------------------------------------------------------------
__global__ __launch_bounds__(256) void k1_x_fill(
    const float* __restrict__ D, const float* __restrict__ W,
    const int* __restrict__ ctx_ids, const int* __restrict__ doc_ids,
    const int* __restrict__ tn, float* __restrict__ x,
    int* __restrict__ cnt, int* __restrict__ idx,
    int* __restrict__ ovc, int* __restrict__ ovf) {
    const int t = threadIdx.x, wave = t >> 6, lane = t & 63;
    const int b = blockIdx.x * 4 + wave;

    if (t < 4 * K) {
        const int p = blockIdx.x * 4 * K + t;
        const int w = tn[p];
        const int pos = atomicAdd(&cnt[w], 1);
        if (pos < CAP) idx[w * CAP + pos] = p;
        else { const int o = atomicAdd(ovc, 1); if (o < OVF_MAX) ovf[o] = p; }
    }

    float2 xx = ((const float2*)(D + (size_t)doc_ids[b] * EMB))[lane];
#pragma unroll
    for (int c = 0; c < CTX; ++c) {
        const float2 w2 = ((const float2*)(W + (size_t)ctx_ids[b * CTX + c] * EMB))[lane];
        xx.x += w2.x;
        xx.y += w2.y;
    }
    ((float2*)(x + (size_t)b * EMB))[lane] = xx;
}

// ---------------------------------------------------------------------------
// K2: stream Wp coalesced once (64-word x 128-dim tile -> LDS), compact the
// tile's referencing pairs into an LDS list, then serve pairs PAIR-PARALLEL:
// wave i takes list entries i, i+4, ... Each iteration independent.
// ---------------------------------------------------------------------------
__global__ __launch_bounds__(256) void k2_dot(
    const float* __restrict__ Wp, const float* __restrict__ x,
    const int* __restrict__ cnt, const int* __restrict__ idx,
    const int* __restrict__ ovc, const int* __restrict__ ovf,
    const int* __restrict__ tn, float* __restrict__ out) {
    __shared__ float tile[TILE_W * TSTRIDE];  // [word][dim], padded
    __shared__ int2 list[TILE_W * CAP];       // {w_local, pair}
    __shared__ int npairs;
    const int t = threadIdx.x, wave = t >> 6, lane = t & 63;
    const int w0 = blockIdx.x * TILE_W;

    if (t == 0) npairs = 0;
    __syncthreads();

    // ---- stage tile (issue the big HBM stream first) ----
    // thread reads float2 = 2 words of one dim; 16 dims per thread.
    const int wi = t & 31, e0 = t >> 5;
    if (w0 + 2 * wi + 1 < N_WORDS) {
#pragma unroll
        for (int j = 0; j < 16; ++j) {
            const int e = e0 + 8 * j;
            const float2 v = *(const float2*)(Wp + (size_t)e * N_WORDS + w0 + 2 * wi);
            tile[(2 * wi) * TSTRIDE + e] = v.x;
            tile[(2 * wi + 1) * TSTRIDE + e] = v.y;
        }
    }

    // ---- compact pair list (wave 0; overlaps staging latency of others) ----
    if (t < TILE_W) {
        const int w = w0 + t;
        if (w < N_WORDS) {
            int c = cnt[w];
            if (c > CAP) c = CAP;
            if (c > 0) {
                const int base = atomicAdd(&npairs, c);
                for (int q = 0; q < c; ++q) list[base + q] = make_int2(t, idx[w * CAP + q]);
            }
        }
    }
    __syncthreads();

    // ---- serve pairs in parallel across waves ----
    const int np = npairs;
#pragma unroll 2
    for (int i = wave; i < np; i += 4) {
        const int2 e = list[i];  // wave-uniform LDS broadcast
        const float2 col = *(const float2*)(tile + e.x * TSTRIDE + 2 * lane);
        const unsigned p = (unsigned)e.y;
        const float2 xv = *(const float2*)(x + (size_t)(p / 6u) * EMB + 2 * lane);
        float s = col.x * xv.x + col.y * xv.y;
#pragma unroll
        for (int off = 32; off > 0; off >>= 1) s += __shfl_down(s, off, 64);
        if (lane == 0) out[p] = s;
    }

    // ---- overflow pairs (expected zero), strided column reads ----
    if (blockIdx.x == 0 && wave == 0) {
        int n = *ovc;
        if (n > OVF_MAX) n = OVF_MAX;
        for (int i = 0; i < n; ++i) {
            const int p = ovf[i];
            const int w = tn[p];
            const float a0 = Wp[(size_t)(2 * lane) * N_WORDS + w];
            const float a1 = Wp[(size_t)(2 * lane + 1) * N_WORDS + w];
            const float2 xv = ((const float2*)(x + (size_t)((unsigned)p / 6u) * EMB))[lane];
            float s = xv.x * a0 + xv.y * a1;
#pragma unroll
            for (int off = 32; off > 0; off >>= 1) s += __shfl_down(s, off, 64);
            if (lane == 0) out[p] = s;
        }
    }
}

// ---------------------------------------------------------------------------
// Fallback (no workspace): direct strided column gather.
// ---------------------------------------------------------------------------
__global__ __launch_bounds__(256) void nce_direct(
    const float* __restrict__ D, const float* __restrict__ W,
    const float* __restrict__ Wp, const int* __restrict__ ctx_ids,
    const int* __restrict__ doc_ids, const int* __restrict__ tn_ids,
    float* __restrict__ out) {
    const int wave = threadIdx.x >> 6, lane = threadIdx.x & 63;
    const int b = blockIdx.x * 4 + wave;
    if (b >= BATCH) return;
    float2 xx = ((const float2*)(D + (size_t)doc_ids[b] * EMB))[lane];
#pragma unroll
    for (int c = 0; c < CTX; ++c) {
        const float2 w2 = ((const float2*)(W + (size_t)ctx_ids[b * CTX + c] * EMB))[lane];
        xx.x += w2.x;
        xx.y += w2.y;
    }
#pragma unroll
    for (int k = 0; k < K; ++k) {
        const int id = tn_ids[b * K + k];
        float s = xx.x * Wp[(size_t)(2 * lane) * N_WORDS + id] +
                  xx.y * Wp[(size_t)(2 * lane + 1) * N_WORDS + id];
#pragma unroll
        for (int off = 32; off > 0; off >>= 1) s += __shfl_down(s, off, 64);
        if (lane == 0) out[b * K + k] = s;
    }
}

extern "C" void kernel_launch(void* const* d_in, const int* in_sizes, int n_in,
                              void* d_out, int out_size, void* d_ws, size_t ws_size,
                              hipStream_t stream) {
    const float* D  = (const float*)d_in[0];
    const float* W  = (const float*)d_in[1];
    const float* Wp = (const float*)d_in[2];
    const int* ctx  = (const int*)d_in[3];
    const int* doc  = (const int*)d_in[4];
    const int* tn   = (const int*)d_in[5];
    float* out = (float*)d_out;

    const size_t x_off   = 0;
    const size_t x_sz    = (size_t)BATCH * EMB * sizeof(float);
    const size_t cnt_off = (x_off + x_sz + 255) & ~(size_t)255;
    const size_t cnt_sz  = (size_t)N_WORDS * sizeof(int);
    const size_t idx_off = (cnt_off + cnt_sz + 255) & ~(size_t)255;
    const size_t idx_sz  = (size_t)N_WORDS * CAP * sizeof(int);
    const size_t ovc_off = (idx_off + idx_sz + 255) & ~(size_t)255;
    const size_t ovf_off = (ovc_off + 256 + 255) & ~(size_t)255;
    const size_t need    = ovf_off + OVF_MAX * sizeof(int);

    if (ws_size >= need) {
        char* ws = (char*)d_ws;
        float* x = (float*)(ws + x_off);
        int* cnt = (int*)(ws + cnt_off);
        int* idx = (int*)(ws + idx_off);
        int* ovc = (int*)(ws + ovc_off);
        int* ovf = (int*)(ws + ovf_off);

        k0_zero<<<(N_WORDS + 255) / 256, 256, 0, stream>>>(cnt, ovc);
        k1_x_fill<<<BATCH / 4, 256, 0, stream>>>(D, W, ctx, doc, tn, x, cnt, idx, ovc, ovf);
        k2_dot<<<(N_WORDS + TILE_W - 1) / TILE_W, 256, 0, stream>>>(Wp, x, cnt, idx, ovc, ovf, tn, out);
    } else {
        nce_direct<<<BATCH / 4, 256, 0, stream>>>(D, W, Wp, ctx, doc, tn, out);
    }
}

// Round 4
// 47.508 us; speedup vs baseline: 1.6120x; 1.4177x over previous
//
#include <hip/hip_runtime.h>

#define N_DOCS 500000
#define N_WORDS 100000
#define EMB 128
#define BATCH 16384
#define CTX 8
#define K 6
#define CAP 16
#define OVF_MAX 1024
#define TILE_W 64
#define S 132  // LDS word stride (floats); even -> b128-aligned, 132%32=4 spreads banks

// ---------------------------------------------------------------------------
// K0: zero per-word counters + overflow counter (ws is poisoned, not zeroed).
// ---------------------------------------------------------------------------
__global__ __launch_bounds__(256) void k0_zero(int* __restrict__ cnt, int* __restrict__ ovc) {
    int i = blockIdx.x * 256 + threadIdx.x;
    if (i < N_WORDS) cnt[i] = 0;
    if (i == 0) *ovc = 0;
}

// ---------------------------------------------------------------------------
// K1: x[b] = D[doc[b]] + sum_c W[ctx[b,c]]  (one wave per b, float2/lane)
//     + inverted-index fill (threads 0..23 file this block's 24 pairs).
// ---------------------------------------------------------------------------
__global__ __launch_bounds__(256) void k1_x_fill(
    const float* __restrict__ D, const float* __restrict__ W,
    const int* __restrict__ ctx_ids, const int* __restrict__ doc_ids,
    const int* __restrict__ tn, float* __restrict__ x,
    int* __restrict__ cnt, int* __restrict__ idx,
    int* __restrict__ ovc, int* __restrict__ ovf) {
    const int t = threadIdx.x, wave = t >> 6, lane = t & 63;
    const int b = blockIdx.x * 4 + wave;

    if (t < 4 * K) {
        const int p = blockIdx.x * 4 * K + t;
        const int w = tn[p];
        const int pos = atomicAdd(&cnt[w], 1);
        if (pos < CAP) idx[w * CAP + pos] = p;
        else { const int o = atomicAdd(ovc, 1); if (o < OVF_MAX) ovf[o] = p; }
    }

    float2 xx = ((const float2*)(D + (size_t)doc_ids[b] * EMB))[lane];
#pragma unroll
    for (int c = 0; c < CTX; ++c) {
        const float2 w2 = ((const float2*)(W + (size_t)ctx_ids[b * CTX + c] * EMB))[lane];
        xx.x += w2.x;
        xx.y += w2.y;
    }
    ((float2*)(x + (size_t)b * EMB))[lane] = xx;
}

// ---------------------------------------------------------------------------
// K2: stream Wp coalesced once (64 words x 128 dims -> LDS word-major),
// compact referencing pairs into packed LDS list, serve QUARTER-WAVE per pair:
// 16 lanes x 8 dims, 2x ds_read_b128 + 2x dwordx4 x-row, 4-step shfl_xor.
// ---------------------------------------------------------------------------
__global__ __launch_bounds__(256) void k2_dot(
    const float* __restrict__ Wp, const float* __restrict__ x,
    const int* __restrict__ cnt, const int* __restrict__ idx,
    const int* __restrict__ ovc, const int* __restrict__ ovf,
    const int* __restrict__ tn, float* __restrict__ out) {
    __shared__ float tile[TILE_W * S];    // 33792 B, [word][dim] padded
    __shared__ int list[TILE_W * CAP];    // 4096 B, packed (wl<<17)|pair
    __shared__ int npairs;
    const int t = threadIdx.x;
    const int w0 = blockIdx.x * TILE_W;

    if (t == 0) npairs = 0;
    __syncthreads();

    // ---- stage: thread t reads float4 = 4 words of dim e; 8 dims per thread.
    {
        const int wi = t & 15, e0 = t >> 4;  // e0 in 0..15
        const int wbase = w0 + 4 * wi;
#pragma unroll
        for (int j = 0; j < 8; ++j) {
            const int e = e0 + 16 * j;
            if (wbase + 3 < N_WORDS) {
                const float4 v = *(const float4*)(Wp + (size_t)e * N_WORDS + wbase);
                tile[(4 * wi + 0) * S + e] = v.x;
                tile[(4 * wi + 1) * S + e] = v.y;
                tile[(4 * wi + 2) * S + e] = v.z;
                tile[(4 * wi + 3) * S + e] = v.w;
            } else {
#pragma unroll
                for (int m = 0; m < 4; ++m)
                    if (wbase + m < N_WORDS)
                        tile[(4 * wi + m) * S + e] = Wp[(size_t)e * N_WORDS + wbase + m];
            }
        }
    }

    // ---- compact pair list (64 threads, ~1 entry each on average) ----
    if (t < TILE_W && w0 + t < N_WORDS) {
        int c = cnt[w0 + t];
        if (c > CAP) c = CAP;
        if (c > 0) {
            const int base = atomicAdd(&npairs, c);
            for (int q = 0; q < c; ++q)
                list[base + q] = (t << 17) | idx[(w0 + t) * CAP + q];
        }
    }
    __syncthreads();

    // ---- serve: quarter-wave (16 lanes) per pair, 16 pairs in flight ----
    const int np = npairs;
    const int qw = t >> 4;   // 0..15
    const int li = t & 15;   // 0..15
    for (int i = qw; i < np; i += 16) {
        const int e = list[i];
        const int wl = e >> 17;
        const unsigned p = (unsigned)(e & 0x1FFFF);
        const float* col = tile + wl * S + 8 * li;
        const float4 c0 = *(const float4*)(col);
        const float4 c1 = *(const float4*)(col + 4);
        const float* xr = x + (size_t)(p / 6u) * EMB + 8 * li;
        const float4 x0 = *(const float4*)(xr);
        const float4 x1 = *(const float4*)(xr + 4);
        float s = c0.x * x0.x + c0.y * x0.y + c0.z * x0.z + c0.w * x0.w +
                  c1.x * x1.x + c1.y * x1.y + c1.z * x1.z + c1.w * x1.w;
        s += __shfl_xor(s, 8);
        s += __shfl_xor(s, 4);
        s += __shfl_xor(s, 2);
        s += __shfl_xor(s, 1);
        if (li == 0) out[p] = s;
    }

    // ---- overflow pairs (expected zero), strided column reads ----
    if (blockIdx.x == 0 && t < 64) {
        int n = *ovc;
        if (n > OVF_MAX) n = OVF_MAX;
        const int lane = t;
        for (int i = 0; i < n; ++i) {
            const int p = ovf[i];
            const int w = tn[p];
            const float a0 = Wp[(size_t)(2 * lane) * N_WORDS + w];
            const float a1 = Wp[(size_t)(2 * lane + 1) * N_WORDS + w];
            const float2 xv = ((const float2*)(x + (size_t)((unsigned)p / 6u) * EMB))[lane];
            float s = xv.x * a0 + xv.y * a1;
#pragma unroll
            for (int off = 32; off > 0; off >>= 1) s += __shfl_down(s, off, 64);
            if (lane == 0) out[p] = s;
        }
    }
}

// ---------------------------------------------------------------------------
// Fallback (no workspace): direct strided column gather.
// ---------------------------------------------------------------------------
__global__ __launch_bounds__(256) void nce_direct(
    const float* __restrict__ D, const float* __restrict__ W,
    const float* __restrict__ Wp, const int* __restrict__ ctx_ids,
    const int* __restrict__ doc_ids, const int* __restrict__ tn_ids,
    float* __restrict__ out) {
    const int wave = threadIdx.x >> 6, lane = threadIdx.x & 63;
    const int b = blockIdx.x * 4 + wave;
    if (b >= BATCH) return;
    float2 xx = ((const float2*)(D + (size_t)doc_ids[b] * EMB))[lane];
#pragma unroll
    for (int c = 0; c < CTX; ++c) {
        const float2 w2 = ((const float2*)(W + (size_t)ctx_ids[b * CTX + c] * EMB))[lane];
        xx.x += w2.x;
        xx.y += w2.y;
    }
#pragma unroll
    for (int k = 0; k < K; ++k) {
        const int id = tn_ids[b * K + k];
        float s = xx.x * Wp[(size_t)(2 * lane) * N_WORDS + id] +
                  xx.y * Wp[(size_t)(2 * lane + 1) * N_WORDS + id];
#pragma unroll
        for (int off = 32; off > 0; off >>= 1) s += __shfl_down(s, off, 64);
        if (lane == 0) out[b * K + k] = s;
    }
}

extern "C" void kernel_launch(void* const* d_in, const int* in_sizes, int n_in,
                              void* d_out, int out_size, void* d_ws, size_t ws_size,
                              hipStream_t stream) {
    const float* D  = (const float*)d_in[0];
    const float* W  = (const float*)d_in[1];
    const float* Wp = (const float*)d_in[2];
    const int* ctx  = (const int*)d_in[3];
    const int* doc  = (const int*)d_in[4];
    const int* tn   = (const int*)d_in[5];
    float* out = (float*)d_out;

    const size_t x_off   = 0;
    const size_t x_sz    = (size_t)BATCH * EMB * sizeof(float);
    const size_t cnt_off = (x_off + x_sz + 255) & ~(size_t)255;
    const size_t cnt_sz  = (size_t)N_WORDS * sizeof(int);
    const size_t idx_off = (cnt_off + cnt_sz + 255) & ~(size_t)255;
    const size_t idx_sz  = (size_t)N_WORDS * CAP * sizeof(int);
    const size_t ovc_off = (idx_off + idx_sz + 255) & ~(size_t)255;
    const size_t ovf_off = (ovc_off + 256 + 255) & ~(size_t)255;
    const size_t need    = ovf_off + OVF_MAX * sizeof(int);

    if (ws_size >= need) {
        char* ws = (char*)d_ws;
        float* x = (float*)(ws + x_off);
        int* cnt = (int*)(ws + cnt_off);
        int* idx = (int*)(ws + idx_off);
        int* ovc = (int*)(ws + ovc_off);
        int* ovf = (int*)(ws + ovf_off);

        k0_zero<<<(N_WORDS + 255) / 256, 256, 0, stream>>>(cnt, ovc);
        k1_x_fill<<<BATCH / 4, 256, 0, stream>>>(D, W, ctx, doc, tn, x, cnt, idx, ovc, ovf);
        k2_dot<<<(N_WORDS + TILE_W - 1) / TILE_W, 256, 0, stream>>>(Wp, x, cnt, idx, ovc, ovf, tn, out);
    } else {
        nce_direct<<<BATCH / 4, 256, 0, stream>>>(D, W, Wp, ctx, doc, tn, out);
    }
}

// Round 5
// 45.770 us; speedup vs baseline: 1.6732x; 1.0380x over previous
//
#include <hip/hip_runtime.h>

#define N_DOCS 500000
#define N_WORDS 100000
#define EMB 128
#define BATCH 16384
#define CTX 8
#define K 6
#define CAP 16
#define OVF_MAX 1024
#define TILE_W 64
#define SB 136  // bf16 tile stride (elements); row byte-stride 272 = 16*17 -> 16B-aligned rows, banks spread

__device__ __forceinline__ unsigned short f2bf(float f) {
    unsigned u = __float_as_uint(f);
    unsigned r = u + 0x7fffu + ((u >> 16) & 1u);  // round-to-nearest-even
    return (unsigned short)(r >> 16);
}
#define BF2F(h) __uint_as_float(((unsigned)(h)) << 16)

// ---------------------------------------------------------------------------
// K1: x[b] = D[doc[b]] + sum_c W[ctx[b,c]]  (one wave per b, float2/lane)
//     + inverted-index fill (threads 0..23 file this block's 24 pairs).
// ---------------------------------------------------------------------------
__global__ __launch_bounds__(256) void k1_x_fill(
    const float* __restrict__ D, const float* __restrict__ W,
    const int* __restrict__ ctx_ids, const int* __restrict__ doc_ids,
    const int* __restrict__ tn, float* __restrict__ x,
    int* __restrict__ cnt, int* __restrict__ idx,
    int* __restrict__ ovc, int* __restrict__ ovf) {
    const int t = threadIdx.x, wave = t >> 6, lane = t & 63;
    const int b = blockIdx.x * 4 + wave;

    if (t < 4 * K) {
        const int p = blockIdx.x * 4 * K + t;
        const int w = tn[p];
        const int pos = atomicAdd(&cnt[w], 1);
        if (pos < CAP) idx[w * CAP + pos] = p;
        else { const int o = atomicAdd(ovc, 1); if (o < OVF_MAX) ovf[o] = p; }
    }

    float2 xx = ((const float2*)(D + (size_t)doc_ids[b] * EMB))[lane];
#pragma unroll
    for (int c = 0; c < CTX; ++c) {
        const float2 w2 = ((const float2*)(W + (size_t)ctx_ids[b * CTX + c] * EMB))[lane];
        xx.x += w2.x;
        xx.y += w2.y;
    }
    ((float2*)(x + (size_t)b * EMB))[lane] = xx;
}

// ---------------------------------------------------------------------------
// K2: stream Wp coalesced once -> bf16 LDS tile [word][dim]; compact pair
// list; serve quarter-wave per pair with a 2-deep software pipeline.
// ---------------------------------------------------------------------------
__global__ __launch_bounds__(256) void k2_dot(
    const float* __restrict__ Wp, const float* __restrict__ x,
    const int* __restrict__ cnt, const int* __restrict__ idx,
    const int* __restrict__ ovc, const int* __restrict__ ovf,
    const int* __restrict__ tn, float* __restrict__ out) {
    __shared__ unsigned short tileb[TILE_W * SB];  // 17408 B
    __shared__ int list[TILE_W * CAP];             // 4096 B, (wl<<17)|pair
    __shared__ int npairs;
    const int t = threadIdx.x;
    const int w0 = blockIdx.x * TILE_W;

    if (t == 0) npairs = 0;
    __syncthreads();

    // ---- stage: thread reads float4 = 4 words of dim e; 8 dims/thread ----
    {
        const int wi = t & 15, e0 = t >> 4;  // e0 0..15
        const int wbase = w0 + 4 * wi;
#pragma unroll
        for (int j = 0; j < 8; ++j) {
            const int e = e0 + 16 * j;
            if (wbase + 3 < N_WORDS) {
                const float4 v = *(const float4*)(Wp + (size_t)e * N_WORDS + wbase);
                tileb[(4 * wi + 0) * SB + e] = f2bf(v.x);
                tileb[(4 * wi + 1) * SB + e] = f2bf(v.y);
                tileb[(4 * wi + 2) * SB + e] = f2bf(v.z);
                tileb[(4 * wi + 3) * SB + e] = f2bf(v.w);
            } else {
#pragma unroll
                for (int m = 0; m < 4; ++m)
                    if (wbase + m < N_WORDS)
                        tileb[(4 * wi + m) * SB + e] = f2bf(Wp[(size_t)e * N_WORDS + wbase + m]);
            }
        }
    }

    // ---- compact pair list ----
    if (t < TILE_W && w0 + t < N_WORDS) {
        int c = cnt[w0 + t];
        if (c > CAP) c = CAP;
        if (c > 0) {
            const int base = atomicAdd(&npairs, c);
            for (int q = 0; q < c; ++q)
                list[base + q] = (t << 17) | idx[(w0 + t) * CAP + q];
        }
    }
    __syncthreads();

    // ---- serve: quarter-wave per pair, 2-deep pipeline ----
    const int np = npairs;
    const int qw = t >> 4, li = t & 15;
    if (np > 0) {
        const int cl = np - 1;
        int iA = qw > cl ? cl : qw;
        int eA = list[iA];
        unsigned pA = (unsigned)(eA & 0x1FFFF);
        uint4 cA = *(const uint4*)(tileb + (eA >> 17) * SB + 8 * li);
        const float* xrA = x + (size_t)(pA / 6u) * EMB + 8 * li;
        float4 xA0 = *(const float4*)xrA;
        float4 xA1 = *(const float4*)(xrA + 4);

        for (int iB = qw + 16; iB - 16 < np; iB += 16) {
            // prefetch B
            const int ib = iB > cl ? cl : iB;
            const int eB = list[ib];
            const unsigned pB = (unsigned)(eB & 0x1FFFF);
            const uint4 cB = *(const uint4*)(tileb + (eB >> 17) * SB + 8 * li);
            const float* xrB = x + (size_t)(pB / 6u) * EMB + 8 * li;
            const float4 xB0 = *(const float4*)xrB;
            const float4 xB1 = *(const float4*)(xrB + 4);
            // consume A
            float s = BF2F(cA.x & 0xffff) * xA0.x + BF2F(cA.x >> 16) * xA0.y +
                      BF2F(cA.y & 0xffff) * xA0.z + BF2F(cA.y >> 16) * xA0.w +
                      BF2F(cA.z & 0xffff) * xA1.x + BF2F(cA.z >> 16) * xA1.y +
                      BF2F(cA.w & 0xffff) * xA1.z + BF2F(cA.w >> 16) * xA1.w;
            s += __shfl_xor(s, 8);
            s += __shfl_xor(s, 4);
            s += __shfl_xor(s, 2);
            s += __shfl_xor(s, 1);
            if (li == 0) out[pA] = s;
            // shift B -> A
            pA = pB; cA = cB; xA0 = xB0; xA1 = xB1;
        }
    }

    // ---- overflow pairs (expected zero), strided column reads ----
    if (blockIdx.x == 0 && t < 64) {
        int n = *ovc;
        if (n > OVF_MAX) n = OVF_MAX;
        const int lane = t;
        for (int i = 0; i < n; ++i) {
            const int p = ovf[i];
            const int w = tn[p];
            const float a0 = Wp[(size_t)(2 * lane) * N_WORDS + w];
            const float a1 = Wp[(size_t)(2 * lane + 1) * N_WORDS + w];
            const float2 xv = ((const float2*)(x + (size_t)((unsigned)p / 6u) * EMB))[lane];
            float s = xv.x * a0 + xv.y * a1;
#pragma unroll
            for (int off = 32; off > 0; off >>= 1) s += __shfl_down(s, off, 64);
            if (lane == 0) out[p] = s;
        }
    }
}

// ---------------------------------------------------------------------------
// Fallback (no workspace): direct strided column gather.
// ---------------------------------------------------------------------------
__global__ __launch_bounds__(256) void nce_direct(
    const float* __restrict__ D, const float* __restrict__ W,
    const float* __restrict__ Wp, const int* __restrict__ ctx_ids,
    const int* __restrict__ doc_ids, const int* __restrict__ tn_ids,
    float* __restrict__ out) {
    const int wave = threadIdx.x >> 6, lane = threadIdx.x & 63;
    const int b = blockIdx.x * 4 + wave;
    if (b >= BATCH) return;
    float2 xx = ((const float2*)(D + (size_t)doc_ids[b] * EMB))[lane];
#pragma unroll
    for (int c = 0; c < CTX; ++c) {
        const float2 w2 = ((const float2*)(W + (size_t)ctx_ids[b * CTX + c] * EMB))[lane];
        xx.x += w2.x;
        xx.y += w2.y;
    }
#pragma unroll
    for (int k = 0; k < K; ++k) {
        const int id = tn_ids[b * K + k];
        float s = xx.x * Wp[(size_t)(2 * lane) * N_WORDS + id] +
                  xx.y * Wp[(size_t)(2 * lane + 1) * N_WORDS + id];
#pragma unroll
        for (int off = 32; off > 0; off >>= 1) s += __shfl_down(s, off, 64);
        if (lane == 0) out[b * K + k] = s;
    }
}

extern "C" void kernel_launch(void* const* d_in, const int* in_sizes, int n_in,
                              void* d_out, int out_size, void* d_ws, size_t ws_size,
                              hipStream_t stream) {
    const float* D  = (const float*)d_in[0];
    const float* W  = (const float*)d_in[1];
    const float* Wp = (const float*)d_in[2];
    const int* ctx  = (const int*)d_in[3];
    const int* doc  = (const int*)d_in[4];
    const int* tn   = (const int*)d_in[5];
    float* out = (float*)d_out;

    const size_t x_off   = 0;
    const size_t x_sz    = (size_t)BATCH * EMB * sizeof(float);
    const size_t cnt_off = (x_off + x_sz + 255) & ~(size_t)255;
    const size_t cnt_sz  = (size_t)N_WORDS * sizeof(int);
    const size_t idx_off = (cnt_off + cnt_sz + 255) & ~(size_t)255;
    const size_t idx_sz  = (size_t)N_WORDS * CAP * sizeof(int);
    const size_t ovc_off = (idx_off + idx_sz + 255) & ~(size_t)255;
    const size_t ovf_off = (ovc_off + 256 + 255) & ~(size_t)255;
    const size_t need    = ovf_off + OVF_MAX * sizeof(int);

    if (ws_size >= need) {
        char* ws = (char*)d_ws;
        float* x = (float*)(ws + x_off);
        int* cnt = (int*)(ws + cnt_off);
        int* idx = (int*)(ws + idx_off);
        int* ovc = (int*)(ws + ovc_off);
        int* ovf = (int*)(ws + ovf_off);

        hipMemsetAsync(cnt, 0, cnt_sz, stream);
        hipMemsetAsync(ovc, 0, sizeof(int), stream);
        k1_x_fill<<<BATCH / 4, 256, 0, stream>>>(D, W, ctx, doc, tn, x, cnt, idx, ovc, ovf);
        k2_dot<<<(N_WORDS + TILE_W - 1) / TILE_W, 256, 0, stream>>>(Wp, x, cnt, idx, ovc, ovf, tn, out);
    } else {
        nce_direct<<<BATCH / 4, 256, 0, stream>>>(D, W, Wp, ctx, doc, tn, out);
    }
}

// Round 6
// 36.493 us; speedup vs baseline: 2.0985x; 1.2542x over previous
//
#include <hip/hip_runtime.h>

#define N_DOCS 500000
#define N_WORDS 100000
#define EMB 128
#define BATCH 16384
#define CTX 8
#define K 6

__device__ __forceinline__ unsigned short f2bf(float f) {
    unsigned u = __float_as_uint(f);
    unsigned r = u + 0x7fffu + ((u >> 16) & 1u);  // round-to-nearest-even
    return (unsigned short)(r >> 16);
}
#define BF2F(h) __uint_as_float(((unsigned)(h)) << 16)

// ---------------------------------------------------------------------------
// Kernel A: transpose Wp [EMB, N_WORDS] f32 -> WpT [N_WORDS, EMB] bf16.
// 32x32 tiles via LDS (pad 33 -> conflict-free both phases).
// Grid (3125, 4), block (32, 8). N_WORDS % 32 == 0, so no bounds checks.
// ---------------------------------------------------------------------------
__global__ __launch_bounds__(256) void transpose_bf16(const float* __restrict__ Wp,
                                                      unsigned short* __restrict__ WpT) {
    __shared__ float tile[32][33];
    const int ctile = blockIdx.x;  // word tile
    const int rtile = blockIdx.y;  // dim tile
    const int tx = threadIdx.x;    // 0..31
    const int ty = threadIdx.y;    // 0..7

    const int col = ctile * 32 + tx;
#pragma unroll
    for (int j = 0; j < 4; ++j) {
        const int row = rtile * 32 + ty + j * 8;
        tile[ty + j * 8][tx] = Wp[(size_t)row * N_WORDS + col];
    }
    __syncthreads();
#pragma unroll
    for (int j = 0; j < 4; ++j) {
        const int r = ty + j * 8;  // word within tile
        WpT[(size_t)(ctile * 32 + r) * EMB + rtile * 32 + tx] = f2bf(tile[tx][r]);
    }
}

// ---------------------------------------------------------------------------
// Kernel B: fused. One wave per b (4 waves/block). b forced wave-uniform via
// readfirstlane so all index loads are scalar (s_load) and row gathers are
// SGPR-base + lane-offset. Lane l holds dims {2l, 2l+1}.
// ---------------------------------------------------------------------------
__global__ __launch_bounds__(256) void nce_fused(const float* __restrict__ D,
                                                 const float* __restrict__ W,
                                                 const unsigned short* __restrict__ WpT,
                                                 const int* __restrict__ ctx_ids,
                                                 const int* __restrict__ doc_ids,
                                                 const int* __restrict__ tn_ids,
                                                 float* __restrict__ out) {
    const int lane = threadIdx.x & 63;
    const int b = __builtin_amdgcn_readfirstlane(blockIdx.x * 4 + (threadIdx.x >> 6));

    const int doc = doc_ids[b];
    float2 xx = ((const float2*)(D + (size_t)doc * EMB))[lane];
#pragma unroll
    for (int c = 0; c < CTX; ++c) {
        const int id = ctx_ids[b * CTX + c];
        const float2 w2 = ((const float2*)(W + (size_t)id * EMB))[lane];
        xx.x += w2.x;
        xx.y += w2.y;
    }

#pragma unroll
    for (int k = 0; k < K; ++k) {
        const int id = tn_ids[b * K + k];
        const ushort2 w2 = ((const ushort2*)(WpT + (size_t)id * EMB))[lane];
        float s = xx.x * BF2F(w2.x) + xx.y * BF2F(w2.y);
#pragma unroll
        for (int off = 32; off > 0; off >>= 1) s += __shfl_xor(s, off, 64);
        if (lane == 0) out[b * K + k] = s;
    }
}

// ---------------------------------------------------------------------------
// Fallback (no workspace): direct strided column gather.
// ---------------------------------------------------------------------------
__global__ __launch_bounds__(256) void nce_direct(
    const float* __restrict__ D, const float* __restrict__ W,
    const float* __restrict__ Wp, const int* __restrict__ ctx_ids,
    const int* __restrict__ doc_ids, const int* __restrict__ tn_ids,
    float* __restrict__ out) {
    const int wave = threadIdx.x >> 6, lane = threadIdx.x & 63;
    const int b = blockIdx.x * 4 + wave;
    if (b >= BATCH) return;
    float2 xx = ((const float2*)(D + (size_t)doc_ids[b] * EMB))[lane];
#pragma unroll
    for (int c = 0; c < CTX; ++c) {
        const float2 w2 = ((const float2*)(W + (size_t)ctx_ids[b * CTX + c] * EMB))[lane];
        xx.x += w2.x;
        xx.y += w2.y;
    }
#pragma unroll
    for (int k = 0; k < K; ++k) {
        const int id = tn_ids[b * K + k];
        float s = xx.x * Wp[(size_t)(2 * lane) * N_WORDS + id] +
                  xx.y * Wp[(size_t)(2 * lane + 1) * N_WORDS + id];
#pragma unroll
        for (int off = 32; off > 0; off >>= 1) s += __shfl_down(s, off, 64);
        if (lane == 0) out[b * K + k] = s;
    }
}

extern "C" void kernel_launch(void* const* d_in, const int* in_sizes, int n_in,
                              void* d_out, int out_size, void* d_ws, size_t ws_size,
                              hipStream_t stream) {
    const float* D  = (const float*)d_in[0];
    const float* W  = (const float*)d_in[1];
    const float* Wp = (const float*)d_in[2];
    const int* ctx  = (const int*)d_in[3];
    const int* doc  = (const int*)d_in[4];
    const int* tn   = (const int*)d_in[5];
    float* out = (float*)d_out;

    const size_t need = (size_t)N_WORDS * EMB * sizeof(unsigned short);  // 25.6 MB
    if (ws_size >= need) {
        unsigned short* WpT = (unsigned short*)d_ws;
        transpose_bf16<<<dim3(N_WORDS / 32, EMB / 32), dim3(32, 8), 0, stream>>>(Wp, WpT);
        nce_fused<<<BATCH / 4, 256, 0, stream>>>(D, W, WpT, ctx, doc, tn, out);
    } else {
        nce_direct<<<BATCH / 4, 256, 0, stream>>>(D, W, Wp, ctx, doc, tn, out);
    }
}